// Round 5
// baseline (2819.063 us; speedup 1.0000x reference)
//
#include <hip/hip_runtime.h>
#include <hip/hip_cooperative_groups.h>
#include <hip/hip_bf16.h>

namespace cg = cooperative_groups;

// Problem constants
#define NB   64     // batch
#define NDEC 12     // decoder steps
#define NF   32     // input features
#define NH   512    // hidden
#define NE   96     // encoder length
#define NT   4      // output dim

__device__ __forceinline__ float bf2f(unsigned short u) {
    return __uint_as_float(((unsigned int)u) << 16);
}
__device__ __forceinline__ unsigned short f2bf(float f) {
    unsigned int u = __float_as_uint(f);
    return (unsigned short)((u + 0x7fffu + ((u >> 16) & 1u)) >> 16);   // RNE
}
__device__ __forceinline__ float fast_tanh(float x) {
    x = fminf(fmaxf(x, -15.f), 15.f);
    float e = __expf(2.f * x);
    return (e - 1.f) / (e + 1.f);
}
__device__ __forceinline__ float fast_sig(float x) {
    return 1.f / (1.f + __expf(-x));
}

// ---------------------------------------------------------------------------
// Init: h0/h1 parity-0 (col [512][64]), h1 row copy [64][512], cur(0) [32][64]
__global__ __launch_bounds__(256) void k_init(const float* __restrict__ hidden,
                                              const float* __restrict__ inputs,
                                              float* __restrict__ h0, float* __restrict__ h1,
                                              float* __restrict__ h1row,
                                              float* __restrict__ cur) {
    int b = blockIdx.x, tid = threadIdx.x;
    for (int k = tid; k < NH; k += 256) {
        float v0 = hidden[b*NH + k];
        float v1 = hidden[NB*NH + b*NH + k];
        h0[k*NB + b] = v0;
        h1[k*NB + b] = v1;
        h1row[b*NH + k] = v1;
    }
    if (tid < NF) cur[tid*NB + b] = inputs[b*NDEC*NF + tid];
}

// ---------------------------------------------------------------------------
// enc_proj[be][g] = sum_h enc[be][h] * W_attn[g][512+h]; stored bf16
__global__ __launch_bounds__(256) void k_encproj(const float* __restrict__ enc,
                                                 const float* __restrict__ Wattn,
                                                 unsigned short* __restrict__ encp) {
    __shared__ float As[64][17];
    __shared__ float Bs[64][17];
    int bx = blockIdx.x & 7;    // g tile
    int by = blockIdx.x >> 3;   // be tile
    int tid = threadIdx.x;
    int tx = tid & 15, ty = tid >> 4;
    int arow = tid >> 2;
    int akk  = (tid & 3) * 4;
    const float* Abase = enc   + (size_t)(by*64 + arow)*NH;
    const float* Bbase = Wattn + (size_t)(bx*64 + arow)*(2*NH) + NH;
    float acc[4][4] = {};
    for (int k0 = 0; k0 < NH; k0 += 16) {
        float4 av = *(const float4*)(Abase + k0 + akk);
        float4 bv = *(const float4*)(Bbase + k0 + akk);
        As[arow][akk+0] = av.x; As[arow][akk+1] = av.y;
        As[arow][akk+2] = av.z; As[arow][akk+3] = av.w;
        Bs[arow][akk+0] = bv.x; Bs[arow][akk+1] = bv.y;
        Bs[arow][akk+2] = bv.z; Bs[arow][akk+3] = bv.w;
        __syncthreads();
        #pragma unroll 4
        for (int k = 0; k < 16; ++k) {
            float a0 = As[ty*4+0][k], a1 = As[ty*4+1][k], a2 = As[ty*4+2][k], a3 = As[ty*4+3][k];
            float b0 = Bs[tx*4+0][k], b1 = Bs[tx*4+1][k], b2 = Bs[tx*4+2][k], b3 = Bs[tx*4+3][k];
            acc[0][0] += a0*b0; acc[0][1] += a0*b1; acc[0][2] += a0*b2; acc[0][3] += a0*b3;
            acc[1][0] += a1*b0; acc[1][1] += a1*b1; acc[1][2] += a1*b2; acc[1][3] += a1*b3;
            acc[2][0] += a2*b0; acc[2][1] += a2*b1; acc[2][2] += a2*b2; acc[2][3] += a2*b3;
            acc[3][0] += a3*b0; acc[3][1] += a3*b1; acc[3][2] += a3*b2; acc[3][3] += a3*b3;
        }
        __syncthreads();
    }
    #pragma unroll
    for (int i = 0; i < 4; ++i)
        #pragma unroll
        for (int j = 0; j < 4; ++j)
            encp[(size_t)(by*64 + ty*4 + i)*NH + bx*64 + tx*4 + j] = f2bf(acc[i][j]);
}

// ---------------------------------------------------------------------------
// GRU phase (device fn): 256 blocks, block covers j = {j0, j0+1}.
// thread = (b = t&63, kq = t>>6); virtual K = [xA(KA) | xB(KB) | hold(512)].
__device__ __forceinline__ void gru_phase(
    const float* __restrict__ Wi, const float* __restrict__ Wh,
    const float* __restrict__ bi, const float* __restrict__ bh,
    const float* __restrict__ xA, int KA,
    const float* __restrict__ xB, int KB,
    const float* __restrict__ hold, float* __restrict__ hnew,
    float* __restrict__ hrow,        // optional row-major copy (may be null)
    int j0, int t)
{
    __shared__ float red[4][64][8];
    int b = t & 63, kq = t >> 6;
    int KIw = KA + KB;
    int KT  = KIw + NH;
    int q   = KT >> 2;
    int k0 = kq*q, k1 = k0 + q;
    const float* a0r[2]; const float* a1r[2]; const float* a2r[2];
    const float* h0r[2]; const float* h1r[2]; const float* h2r[2];
    #pragma unroll
    for (int jl = 0; jl < 2; ++jl) {
        int j = j0 + jl;
        a0r[jl] = Wi + (size_t)j*KIw;
        a1r[jl] = Wi + (size_t)(NH + j)*KIw;
        a2r[jl] = Wi + (size_t)(2*NH + j)*KIw;
        h0r[jl] = Wh + (size_t)j*NH;
        h1r[jl] = Wh + (size_t)(NH + j)*NH;
        h2r[jl] = Wh + (size_t)(2*NH + j)*NH;
    }
    float s0[2] = {0.f,0.f}, s1[2] = {0.f,0.f}, a2[2] = {0.f,0.f}, g2[2] = {0.f,0.f};
    int e1 = min(k1, KA);
    #pragma unroll 4
    for (int k = k0; k < e1; ++k) {
        float x = xA[k*NB + b];
        #pragma unroll
        for (int jl = 0; jl < 2; ++jl) {
            s0[jl] += a0r[jl][k]*x; s1[jl] += a1r[jl][k]*x; a2[jl] += a2r[jl][k]*x;
        }
    }
    int b2 = max(k0, KA), e2 = min(k1, KIw);
    #pragma unroll 4
    for (int k = b2; k < e2; ++k) {
        float x = xB[(k - KA)*NB + b];
        #pragma unroll
        for (int jl = 0; jl < 2; ++jl) {
            s0[jl] += a0r[jl][k]*x; s1[jl] += a1r[jl][k]*x; a2[jl] += a2r[jl][k]*x;
        }
    }
    int b3 = max(k0, KIw);
    #pragma unroll 4
    for (int k = b3; k < k1; ++k) {
        int kh = k - KIw;
        float hv = hold[kh*NB + b];
        #pragma unroll
        for (int jl = 0; jl < 2; ++jl) {
            s0[jl] += h0r[jl][kh]*hv; s1[jl] += h1r[jl][kh]*hv; g2[jl] += h2r[jl][kh]*hv;
        }
    }
    #pragma unroll
    for (int jl = 0; jl < 2; ++jl) {
        red[kq][b][jl*4+0] = s0[jl]; red[kq][b][jl*4+1] = s1[jl];
        red[kq][b][jl*4+2] = a2[jl]; red[kq][b][jl*4+3] = g2[jl];
    }
    __syncthreads();
    if (t < 128) {
        int jl = t >> 6, bb = t & 63, j = j0 + jl;
        float S0 = 0.f, S1 = 0.f, A2 = 0.f, G2 = 0.f;
        #pragma unroll
        for (int q4 = 0; q4 < 4; ++q4) {
            S0 += red[q4][bb][jl*4+0]; S1 += red[q4][bb][jl*4+1];
            A2 += red[q4][bb][jl*4+2]; G2 += red[q4][bb][jl*4+3];
        }
        float r = fast_sig(S0 + bi[j] + bh[j]);
        float z = fast_sig(S1 + bi[NH + j] + bh[NH + j]);
        float n = fast_tanh(A2 + bi[2*NH + j] + r*(G2 + bh[2*NH + j]));
        float hp = hold[j*NB + bb];
        float hv = (1.f - z)*n + z*hp;
        hnew[j*NB + bb] = hv;
        if (hrow) hrow[bb*NH + j] = hv;
    }
    __syncthreads();
}

// ---------------------------------------------------------------------------
// Persistent cooperative decode loop: 256 blocks x 256 threads.
__global__ __launch_bounds__(256) void k_decode(
    const float* __restrict__ inputs, const int* __restrict__ tgt,
    const float* __restrict__ Wattn, const float* __restrict__ battn,
    const float* __restrict__ vattn,
    const float* __restrict__ Wi0, const float* __restrict__ Wh0,
    const float* __restrict__ bi0, const float* __restrict__ bh0,
    const float* __restrict__ Wi1, const float* __restrict__ Wh1,
    const float* __restrict__ bi1, const float* __restrict__ bh1,
    const float* __restrict__ Wout, const float* __restrict__ bout,
    const unsigned short* __restrict__ encp, const float* __restrict__ enc,
    float* __restrict__ h0c, float* __restrict__ h1c, float* __restrict__ h1row,
    float* __restrict__ attb, float* __restrict__ peb, float* __restrict__ Dpart,
    float* __restrict__ wsn, float* __restrict__ curc, float* __restrict__ out)
{
    cg::grid_group grid = cg::this_grid();
    int blk = blockIdx.x, t = threadIdx.x;
    int lane = t & 63, w = t >> 6;

    __shared__ float h1s[NH];
    __shared__ float part[64][4];
    __shared__ float outsh[NT];
    __shared__ float atts[NH];
    __shared__ float vs[NH];
    __shared__ float pes[NE];
    __shared__ float comb[128][2];
    __shared__ float invDs;

    for (int s = 0; s <= NDEC; ++s) {
        int par = s & 1;
        const float* h1cur = h1c + par*NH*NB;

        // ---------------- Phase A: out-proj(s-1) + cur(s) + att GEMM ----------------
        int bA = blk >> 2, gsA = blk & 3;
        h1s[t]       = h1row[bA*NH + t];
        h1s[t + 256] = h1row[bA*NH + t + 256];
        __syncthreads();

        if (gsA == 0 && s > 0) {
            const float* wr = Wout + (size_t)w*(2*NH + NF);
            float o = 0.f;
            for (int c = lane; c < 2*NH + NF; c += 64) {
                float x;
                if (c < NH)        x = h1s[c];
                else if (c < 2*NH) x = wsn[(c - NH)*NB + bA];
                else               x = curc[(c - 2*NH)*NB + bA];
                o += wr[c] * x;
            }
            #pragma unroll
            for (int off = 32; off; off >>= 1) o += __shfl_down(o, off);
            if (lane == 0) {
                o += bout[w];
                outsh[w] = o;
                out[bA*(NDEC*NT) + (s-1)*NT + w] = o;
            }
            __syncthreads();
            if (s < NDEC) {
                if (t < NF) curc[t*NB + bA] = inputs[bA*(NDEC*NF) + (s-1)*NF + t];
                __syncthreads();
                if (t < NT) curc[tgt[t]*NB + bA] = outsh[t];
            }
        }
        if (s == NDEC) break;   // uniform across all blocks; no further syncs

        {   // att[b][g] for g in [gsA*128, gsA*128+128)
            int gl = t >> 2, kq = t & 3;
            #pragma unroll
            for (int g2i = 0; g2i < 2; ++g2i) {
                int gt = gsA*2 + g2i;
                const float* wr = Wattn + (size_t)(gt*64 + gl)*(2*NH) + kq*128;
                const float* hh = h1s + kq*128;
                float acc = 0.f;
                #pragma unroll 8
                for (int i = 0; i < 128; i += 4) {
                    float4 w4 = *(const float4*)(wr + i);
                    acc += w4.x*hh[i] + w4.y*hh[i+1] + w4.z*hh[i+2] + w4.w*hh[i+3];
                }
                __syncthreads();
                part[gl][kq] = acc;
                __syncthreads();
                if (t < 64)
                    attb[bA*NH + gt*64 + t] =
                        part[t][0] + part[t][1] + part[t][2] + part[t][3] + battn[gt*64 + t];
            }
        }
        grid.sync();

        // ---------------- Phase B: scores -> pe, partial denominators ----------------
        {
            int bB = blk >> 2, eq = blk & 3;
            atts[t]       = attb[bB*NH + t];
            atts[t + 256] = attb[bB*NH + t + 256];
            vs[t]         = vattn[t];
            vs[t + 256]   = vattn[t + 256];
            __syncthreads();
            float mysum = 0.f;
            for (int el = w; el < 24; el += 4) {
                int e = eq*24 + el;
                const unsigned short* ep = encp + (size_t)(bB*NE + e)*NH + lane*8;
                uint4 u = *(const uint4*)ep;
                int gb = lane*8;
                float sacc = 0.f;
                sacc += fast_tanh(__uint_as_float(u.x << 16)          + atts[gb+0]) * vs[gb+0];
                sacc += fast_tanh(__uint_as_float(u.x & 0xffff0000u)  + atts[gb+1]) * vs[gb+1];
                sacc += fast_tanh(__uint_as_float(u.y << 16)          + atts[gb+2]) * vs[gb+2];
                sacc += fast_tanh(__uint_as_float(u.y & 0xffff0000u)  + atts[gb+3]) * vs[gb+3];
                sacc += fast_tanh(__uint_as_float(u.z << 16)          + atts[gb+4]) * vs[gb+4];
                sacc += fast_tanh(__uint_as_float(u.z & 0xffff0000u)  + atts[gb+5]) * vs[gb+5];
                sacc += fast_tanh(__uint_as_float(u.w << 16)          + atts[gb+6]) * vs[gb+6];
                sacc += fast_tanh(__uint_as_float(u.w & 0xffff0000u)  + atts[gb+7]) * vs[gb+7];
                #pragma unroll
                for (int off = 32; off; off >>= 1) sacc += __shfl_down(sacc, off);
                if (lane == 0) {
                    float p = __expf(sacc);     // |score| small: no max-subtract needed
                    peb[bB*NE + e] = p;
                    mysum += p;
                }
            }
            if (lane == 0) part[w][0] = mysum;
            __syncthreads();
            if (t == 0)
                Dpart[bB*4 + eq] = part[0][0] + part[1][0] + part[2][0] + part[3][0];
        }
        grid.sync();

        // ---------------- Phase C: normalized ws [512][64] ----------------
        {
            int bC = blk >> 2, hq = blk & 3;
            if (t < NE) pes[t] = peb[bC*NE + t];
            if (t == 0)
                invDs = 1.f / (Dpart[bC*4] + Dpart[bC*4+1] + Dpart[bC*4+2] + Dpart[bC*4+3]);
            __syncthreads();
            int hl = t & 127, eh = t >> 7;
            int h = hq*128 + hl;
            const float* eb = enc + ((size_t)bC*NE + eh*48)*NH + h;
            float acc = 0.f;
            #pragma unroll 4
            for (int e = 0; e < 48; ++e) acc += pes[eh*48 + e] * eb[(size_t)e*NH];
            comb[hl][eh] = acc;
            __syncthreads();
            if (t < 128) wsn[(hq*128 + t)*NB + bC] = (comb[t][0] + comb[t][1]) * invDs;
        }
        grid.sync();

        // ---------------- Phase D: GRU layer 0 ----------------
        const float* h0cur = h0c + par*NH*NB;
        float* h0new = h0c + (par^1)*NH*NB;
        gru_phase(Wi0, Wh0, bi0, bh0, curc, NF, wsn, NH, h0cur, h0new, nullptr, blk*2, t);
        grid.sync();

        // ---------------- Phase E: GRU layer 1 (input = h0new only) ----------------
        float* h1new = h1c + (par^1)*NH*NB;
        gru_phase(Wi1, Wh1, bi1, bh1, h0new, NH, nullptr, 0, h1cur, h1new, h1row, blk*2, t);
        grid.sync();
    }
}

// ---------------------------------------------------------------------------
extern "C" void kernel_launch(void* const* d_in, const int* in_sizes, int n_in,
                              void* d_out, int out_size, void* d_ws, size_t ws_size,
                              hipStream_t stream) {
    const float* inputs = (const float*)d_in[0];
    const float* hidden = (const float*)d_in[1];
    const float* enc    = (const float*)d_in[2];
    const int*   tgt    = (const int*)d_in[3];
    const float* Wattn  = (const float*)d_in[4];
    const float* battn  = (const float*)d_in[5];
    const float* vattn  = (const float*)d_in[6];
    const float* Wi0    = (const float*)d_in[7];
    const float* Wh0    = (const float*)d_in[8];
    const float* bi0    = (const float*)d_in[9];
    const float* bh0    = (const float*)d_in[10];
    const float* Wi1    = (const float*)d_in[11];
    const float* Wh1    = (const float*)d_in[12];
    const float* bi1    = (const float*)d_in[13];
    const float* bh1    = (const float*)d_in[14];
    const float* Wout   = (const float*)d_in[15];
    const float* bout   = (const float*)d_in[16];
    float* out = (float*)d_out;

    // Workspace: fp32 state (~0.95 MB) + bf16 enc_proj (6.29 MB) ≈ 7.24 MB
    float* h0c   = (float*)d_ws;              // 2 x [512][64]
    float* h1c   = h0c + 2*NH*NB;             // 2 x [512][64]
    float* h1row = h1c + 2*NH*NB;             // [64][512]
    float* attb  = h1row + NB*NH;             // [64][512]
    float* peb   = attb + NB*NH;              // [64][96]
    float* Dpart = peb + NB*NE;               // [64][4]
    float* wsn   = Dpart + NB*4;              // [512][64]
    float* curc  = wsn + NH*NB;               // [32][64]
    unsigned short* encp = (unsigned short*)(curc + NF*NB);  // [6144][512] bf16

    k_init<<<NB, 256, 0, stream>>>(hidden, inputs, h0c, h1c, h1row, curc);
    k_encproj<<<768, 256, 0, stream>>>(enc, Wattn, encp);

    void* args[] = {
        (void*)&inputs, (void*)&tgt, (void*)&Wattn, (void*)&battn, (void*)&vattn,
        (void*)&Wi0, (void*)&Wh0, (void*)&bi0, (void*)&bh0,
        (void*)&Wi1, (void*)&Wh1, (void*)&bi1, (void*)&bh1,
        (void*)&Wout, (void*)&bout, (void*)&encp, (void*)&enc,
        (void*)&h0c, (void*)&h1c, (void*)&h1row,
        (void*)&attb, (void*)&peb, (void*)&Dpart,
        (void*)&wsn, (void*)&curc, (void*)&out
    };
    hipLaunchCooperativeKernel((void*)k_decode, dim3(256), dim3(256), args, 0, stream);
}

// Round 6
// 1227.981 us; speedup vs baseline: 2.2957x; 2.2957x over previous
//
#include <hip/hip_runtime.h>
#include <hip/hip_bf16.h>

// Problem constants
#define NB   64     // batch
#define NDEC 12     // decoder steps
#define NF   32     // input features
#define NH   512    // hidden
#define NE   96     // encoder length
#define NT   4      // output dim

__device__ __forceinline__ float bf2f(unsigned short u) {
    return __uint_as_float(((unsigned int)u) << 16);
}
__device__ __forceinline__ unsigned short f2bf(float f) {
    unsigned int u = __float_as_uint(f);
    return (unsigned short)((u + 0x7fffu + ((u >> 16) & 1u)) >> 16);   // RNE
}
__device__ __forceinline__ float fast_tanh(float x) {
    x = fminf(fmaxf(x, -15.f), 15.f);
    float e = __expf(2.f * x);
    return (e - 1.f) / (e + 1.f);
}
__device__ __forceinline__ float fast_sig(float x) {
    return 1.f / (1.f + __expf(-x));
}

// ---------------------------------------------------------------------------
// Init: h0/h1 parity-0 (col [512][64]), h1 row copy [64][512], cur(0) [32][64]
__global__ __launch_bounds__(256) void k_init(const float* __restrict__ hidden,
                                              const float* __restrict__ inputs,
                                              float* __restrict__ h0, float* __restrict__ h1,
                                              float* __restrict__ h1row,
                                              float* __restrict__ cur) {
    int b = blockIdx.x, tid = threadIdx.x;
    for (int k = tid; k < NH; k += 256) {
        float v0 = hidden[b*NH + k];
        float v1 = hidden[NB*NH + b*NH + k];
        h0[k*NB + b] = v0;
        h1[k*NB + b] = v1;
        h1row[b*NH + k] = v1;
    }
    if (tid < NF) cur[tid*NB + b] = inputs[b*NDEC*NF + tid];
}

// ---------------------------------------------------------------------------
// enc_proj[be][g] = sum_h enc[be][h] * W_attn[g][512+h]; stored bf16
__global__ __launch_bounds__(256) void k_encproj(const float* __restrict__ enc,
                                                 const float* __restrict__ Wattn,
                                                 unsigned short* __restrict__ encp) {
    __shared__ float As[64][17];
    __shared__ float Bs[64][17];
    int bx = blockIdx.x & 7;    // g tile
    int by = blockIdx.x >> 3;   // be tile
    int tid = threadIdx.x;
    int tx = tid & 15, ty = tid >> 4;
    int arow = tid >> 2;
    int akk  = (tid & 3) * 4;
    const float* Abase = enc   + (size_t)(by*64 + arow)*NH;
    const float* Bbase = Wattn + (size_t)(bx*64 + arow)*(2*NH) + NH;
    float acc[4][4] = {};
    for (int k0 = 0; k0 < NH; k0 += 16) {
        float4 av = *(const float4*)(Abase + k0 + akk);
        float4 bv = *(const float4*)(Bbase + k0 + akk);
        As[arow][akk+0] = av.x; As[arow][akk+1] = av.y;
        As[arow][akk+2] = av.z; As[arow][akk+3] = av.w;
        Bs[arow][akk+0] = bv.x; Bs[arow][akk+1] = bv.y;
        Bs[arow][akk+2] = bv.z; Bs[arow][akk+3] = bv.w;
        __syncthreads();
        #pragma unroll 4
        for (int k = 0; k < 16; ++k) {
            float a0 = As[ty*4+0][k], a1 = As[ty*4+1][k], a2 = As[ty*4+2][k], a3 = As[ty*4+3][k];
            float b0 = Bs[tx*4+0][k], b1 = Bs[tx*4+1][k], b2 = Bs[tx*4+2][k], b3 = Bs[tx*4+3][k];
            acc[0][0] += a0*b0; acc[0][1] += a0*b1; acc[0][2] += a0*b2; acc[0][3] += a0*b3;
            acc[1][0] += a1*b0; acc[1][1] += a1*b1; acc[1][2] += a1*b2; acc[1][3] += a1*b3;
            acc[2][0] += a2*b0; acc[2][1] += a2*b1; acc[2][2] += a2*b2; acc[2][3] += a2*b3;
            acc[3][0] += a3*b0; acc[3][1] += a3*b1; acc[3][2] += a3*b2; acc[3][3] += a3*b3;
        }
        __syncthreads();
    }
    #pragma unroll
    for (int i = 0; i < 4; ++i)
        #pragma unroll
        for (int j = 0; j < 4; ++j)
            encp[(size_t)(by*64 + ty*4 + i)*NH + bx*64 + tx*4 + j] = f2bf(acc[i][j]);
}

// ---------------------------------------------------------------------------
// Fused per-step attention kernel: one block per batch element, 1024 threads.
// Does: out-proj(s-1) + cur(s) update + att GEMV + scores/softmax + ws.
// do_att=0: final pass, out-proj only.
__global__ __launch_bounds__(1024) void k_step(
    const float* __restrict__ inputs, const int* __restrict__ tgt,
    const float* __restrict__ Wattn, const float* __restrict__ battn,
    const float* __restrict__ vattn,
    const float* __restrict__ Wout, const float* __restrict__ bout,
    const unsigned short* __restrict__ encp, const float* __restrict__ enc,
    const float* __restrict__ h1row,
    float* __restrict__ wsrow, float* __restrict__ wscol,
    float* __restrict__ curc, float* __restrict__ out,
    int s, int do_att)
{
    int b = blockIdx.x, t = threadIdx.x;
    int lane = t & 63, widx = t >> 6;
    __shared__ float h1s[NH], wsp[NH], vs[NH], atts[NH];
    __shared__ float pes[NE];
    __shared__ float combA[NH], combB[NH];
    __shared__ float outsh[NT];
    __shared__ float invD_sh;

    if (t < NH) { h1s[t] = h1row[b*NH + t]; vs[t] = vattn[t]; }
    else        { wsp[t - NH] = wsrow[b*NH + (t - NH)]; }
    __syncthreads();

    if (s > 0) {
        // out(s-1)[b][w] = [h1(s) | ws(s-1) | cur(s-1)] . W_out[w] + b_out[w]
        if (widx < NT) {
            const float* wr = Wout + (size_t)widx*(2*NH + NF);
            float o = 0.f;
            for (int c = lane; c < 2*NH + NF; c += 64) {
                float x = (c < NH) ? h1s[c]
                        : (c < 2*NH ? wsp[c - NH] : curc[(c - 2*NH)*NB + b]);
                o += wr[c]*x;
            }
            #pragma unroll
            for (int off = 32; off; off >>= 1) o += __shfl_down(o, off);
            if (lane == 0) {
                o += bout[widx];
                outsh[widx] = o;
                out[b*(NDEC*NT) + (s-1)*NT + widx] = o;
            }
        }
        __syncthreads();
        if (do_att) {
            if (t < NF) curc[t*NB + b] = inputs[b*(NDEC*NF) + (s-1)*NF + t];
            __syncthreads();
            if (t < NT) curc[tgt[t]*NB + b] = outsh[t];
        }
    }
    if (!do_att) return;

    // att[g] = h1 . Wa_h[g] + battn[g]; thread = (g = t>>1, K-half = t&1)
    {
        int g = t >> 1, half = t & 1;
        const float* wr = Wattn + (size_t)g*(2*NH) + half*256;
        const float* hh = h1s + half*256;
        float acc = 0.f;
        #pragma unroll 8
        for (int i = 0; i < 256; i += 4) {
            float4 w4 = *(const float4*)(wr + i);
            acc += w4.x*hh[i] + w4.y*hh[i+1] + w4.z*hh[i+2] + w4.w*hh[i+3];
        }
        acc += __shfl_xor(acc, 1);
        if (half == 0) atts[g] = acc + battn[g];
    }
    __syncthreads();

    // scores -> exp (no max-subtract: |score| <= sum|v| small)
    {
        float ar[8], vr[8];
        #pragma unroll
        for (int i = 0; i < 8; ++i) { ar[i] = atts[lane*8 + i]; vr[i] = vs[lane*8 + i]; }
        for (int it = 0; it < 6; ++it) {
            int e = widx + it*16;
            const unsigned short* ep = encp + ((size_t)(b*NE + e))*NH + lane*8;
            uint4 u = *(const uint4*)ep;
            float sacc;
            sacc  = fast_tanh(__uint_as_float(u.x << 16)         + ar[0]) * vr[0];
            sacc += fast_tanh(__uint_as_float(u.x & 0xffff0000u) + ar[1]) * vr[1];
            sacc += fast_tanh(__uint_as_float(u.y << 16)         + ar[2]) * vr[2];
            sacc += fast_tanh(__uint_as_float(u.y & 0xffff0000u) + ar[3]) * vr[3];
            sacc += fast_tanh(__uint_as_float(u.z << 16)         + ar[4]) * vr[4];
            sacc += fast_tanh(__uint_as_float(u.z & 0xffff0000u) + ar[5]) * vr[5];
            sacc += fast_tanh(__uint_as_float(u.w << 16)         + ar[6]) * vr[6];
            sacc += fast_tanh(__uint_as_float(u.w & 0xffff0000u) + ar[7]) * vr[7];
            #pragma unroll
            for (int off = 32; off; off >>= 1) sacc += __shfl_down(sacc, off);
            if (lane == 0) pes[e] = __expf(sacc);
        }
    }
    __syncthreads();

    // denominator (wave 0)
    if (t < 64) {
        float v = pes[t] + ((t < 32) ? pes[64 + t] : 0.f);
        #pragma unroll
        for (int off = 32; off; off >>= 1) v += __shfl_down(v, off);
        if (t == 0) invD_sh = 1.f / v;
    }
    __syncthreads();

    // ws[k] = sum_e p[e] * enc[b,e,k]; thread = (k = t&511, e-half = t>>9)
    {
        int k = t & 511, half = t >> 9;
        const float* eb = enc + ((size_t)b*NE + half*48)*NH + k;
        float acc = 0.f;
        #pragma unroll 4
        for (int e = 0; e < 48; ++e) acc += pes[half*48 + e] * eb[(size_t)e*NH];
        if (half == 0) combA[k] = acc; else combB[k] = acc;
    }
    __syncthreads();
    if (t < NH) {
        float v = (combA[t] + combB[t]) * invD_sh;
        wsrow[b*NH + t] = v;
        wscol[t*NB + b] = v;
    }
}

// ---------------------------------------------------------------------------
// GRU: 512 blocks (block = one j), thread = (b = t&63, K-quarter = t>>6).
// Virtual K = [xA(KA) | xB(KB) | hold(512)]; float4 weight loads.
// All segment boundaries are multiples of 4 for KA in {32, 512}.
__global__ __launch_bounds__(256) void k_gru(
    const float* __restrict__ Wi, const float* __restrict__ Wh,
    const float* __restrict__ bi, const float* __restrict__ bh,
    const float* __restrict__ xA, int KA,
    const float* __restrict__ xB, int KB,
    const float* __restrict__ hold, float* __restrict__ hnew,
    float* __restrict__ hrow)
{
    int j = blockIdx.x;
    int t = threadIdx.x, b = t & 63, kq = t >> 6;
    int KIw = KA + KB;
    int KT  = KIw + NH;
    int q   = KT >> 2;
    int k0 = kq*q, k1 = k0 + q;
    const float* w0 = Wi + (size_t)j*KIw;
    const float* w1 = Wi + (size_t)(NH + j)*KIw;
    const float* w2 = Wi + (size_t)(2*NH + j)*KIw;
    const float* v0 = Wh + (size_t)j*NH;
    const float* v1 = Wh + (size_t)(NH + j)*NH;
    const float* v2 = Wh + (size_t)(2*NH + j)*NH;
    float s0 = 0.f, s1 = 0.f, a2 = 0.f, g2 = 0.f;

    // segment 1: xA
    int e1 = min(k1, KA);
    #pragma unroll 2
    for (int k = k0; k < e1; k += 4) {
        float4 q0 = *(const float4*)(w0 + k);
        float4 q1 = *(const float4*)(w1 + k);
        float4 q2 = *(const float4*)(w2 + k);
        float x0 = xA[(k+0)*NB + b], x1 = xA[(k+1)*NB + b];
        float x2 = xA[(k+2)*NB + b], x3 = xA[(k+3)*NB + b];
        s0 += q0.x*x0 + q0.y*x1 + q0.z*x2 + q0.w*x3;
        s1 += q1.x*x0 + q1.y*x1 + q1.z*x2 + q1.w*x3;
        a2 += q2.x*x0 + q2.y*x1 + q2.z*x2 + q2.w*x3;
    }
    // segment 2: xB
    int b2 = max(k0, KA), e2 = min(k1, KIw);
    #pragma unroll 2
    for (int k = b2; k < e2; k += 4) {
        float4 q0 = *(const float4*)(w0 + k);
        float4 q1 = *(const float4*)(w1 + k);
        float4 q2 = *(const float4*)(w2 + k);
        int kx = k - KA;
        float x0 = xB[(kx+0)*NB + b], x1 = xB[(kx+1)*NB + b];
        float x2 = xB[(kx+2)*NB + b], x3 = xB[(kx+3)*NB + b];
        s0 += q0.x*x0 + q0.y*x1 + q0.z*x2 + q0.w*x3;
        s1 += q1.x*x0 + q1.y*x1 + q1.z*x2 + q1.w*x3;
        a2 += q2.x*x0 + q2.y*x1 + q2.z*x2 + q2.w*x3;
    }
    // segment 3: hold (recurrent)
    int b3 = max(k0, KIw);
    #pragma unroll 2
    for (int k = b3; k < k1; k += 4) {
        int kh = k - KIw;
        float4 q0 = *(const float4*)(v0 + kh);
        float4 q1 = *(const float4*)(v1 + kh);
        float4 q2 = *(const float4*)(v2 + kh);
        float x0 = hold[(kh+0)*NB + b], x1 = hold[(kh+1)*NB + b];
        float x2 = hold[(kh+2)*NB + b], x3 = hold[(kh+3)*NB + b];
        s0 += q0.x*x0 + q0.y*x1 + q0.z*x2 + q0.w*x3;
        s1 += q1.x*x0 + q1.y*x1 + q1.z*x2 + q1.w*x3;
        g2 += q2.x*x0 + q2.y*x1 + q2.z*x2 + q2.w*x3;
    }

    __shared__ float red[4][64][4];
    red[kq][b][0] = s0; red[kq][b][1] = s1; red[kq][b][2] = a2; red[kq][b][3] = g2;
    __syncthreads();
    if (t < 64) {
        float S0 = 0.f, S1 = 0.f, A2 = 0.f, G2 = 0.f;
        #pragma unroll
        for (int q4 = 0; q4 < 4; ++q4) {
            S0 += red[q4][t][0]; S1 += red[q4][t][1];
            A2 += red[q4][t][2]; G2 += red[q4][t][3];
        }
        float r = fast_sig(S0 + bi[j] + bh[j]);
        float z = fast_sig(S1 + bi[NH + j] + bh[NH + j]);
        float n = fast_tanh(A2 + bi[2*NH + j] + r*(G2 + bh[2*NH + j]));
        float hp = hold[j*NB + t];
        float hv = (1.f - z)*n + z*hp;
        hnew[j*NB + t] = hv;
        if (hrow) hrow[t*NH + j] = hv;
    }
}

// ---------------------------------------------------------------------------
extern "C" void kernel_launch(void* const* d_in, const int* in_sizes, int n_in,
                              void* d_out, int out_size, void* d_ws, size_t ws_size,
                              hipStream_t stream) {
    const float* inputs = (const float*)d_in[0];
    const float* hidden = (const float*)d_in[1];
    const float* enc    = (const float*)d_in[2];
    const int*   tgt    = (const int*)d_in[3];
    const float* Wattn  = (const float*)d_in[4];
    const float* battn  = (const float*)d_in[5];
    const float* vattn  = (const float*)d_in[6];
    const float* Wi0    = (const float*)d_in[7];
    const float* Wh0    = (const float*)d_in[8];
    const float* bi0    = (const float*)d_in[9];
    const float* bh0    = (const float*)d_in[10];
    const float* Wi1    = (const float*)d_in[11];
    const float* Wh1    = (const float*)d_in[12];
    const float* bi1    = (const float*)d_in[13];
    const float* bh1    = (const float*)d_in[14];
    const float* Wout   = (const float*)d_in[15];
    const float* bout   = (const float*)d_in[16];
    float* out = (float*)d_out;

    // Workspace: fp32 state (~0.93 MB) + bf16 enc_proj (6.29 MB) ≈ 7.2 MB
    float* h0c   = (float*)d_ws;              // 2 x [512][64]
    float* h1c   = h0c + 2*NH*NB;             // 2 x [512][64]
    float* h1row = h1c + 2*NH*NB;             // [64][512]
    float* wsrow = h1row + NB*NH;             // [64][512]
    float* wscol = wsrow + NB*NH;             // [512][64]
    float* curc  = wscol + NH*NB;             // [32][64]
    unsigned short* encp = (unsigned short*)(curc + NF*NB);  // [6144][512] bf16

    k_init<<<NB, 256, 0, stream>>>(hidden, inputs, h0c, h1c, h1row, curc);
    k_encproj<<<768, 256, 0, stream>>>(enc, Wattn, encp);

    for (int s = 0; s < NDEC; ++s) {
        int par = s & 1;
        k_step<<<NB, 1024, 0, stream>>>(inputs, tgt, Wattn, battn, vattn, Wout, bout,
                                        encp, enc, h1row, wsrow, wscol, curc, out, s, 1);
        k_gru<<<NH, 256, 0, stream>>>(Wi0, Wh0, bi0, bh0,
                                      curc, NF, wscol, NH,
                                      h0c + par*NH*NB, h0c + (par^1)*NH*NB, nullptr);
        k_gru<<<NH, 256, 0, stream>>>(Wi1, Wh1, bi1, bh1,
                                      h0c + (par^1)*NH*NB, NH, nullptr, 0,
                                      h1c + par*NH*NB, h1c + (par^1)*NH*NB, h1row);
    }
    // Final out(11) projection only; h1row holds h1(12)
    k_step<<<NB, 1024, 0, stream>>>(inputs, tgt, Wattn, battn, vattn, Wout, bout,
                                    encp, enc, h1row, wsrow, wscol, curc, out, NDEC, 0);
}

// Round 7
// 1068.497 us; speedup vs baseline: 2.6383x; 1.1493x over previous
//
#include <hip/hip_runtime.h>
#include <hip/hip_fp16.h>

// Problem constants
#define NB   64     // batch
#define NDEC 12     // decoder steps
#define NF   32     // input features
#define NH   512    // hidden
#define NE   96     // encoder length
#define NT   4      // output dim

__device__ __forceinline__ float fast_tanh(float x) {
    x = fminf(fmaxf(x, -15.f), 15.f);
    float e = __expf(2.f * x);
    return (e - 1.f) / (e + 1.f);
}
__device__ __forceinline__ float fast_sig(float x) {
    return 1.f / (1.f + __expf(-x));
}

// ---------------------------------------------------------------------------
// One-time fp32 -> fp16 converts
__global__ __launch_bounds__(256) void k_cvt(const float* __restrict__ src,
                                             __half* __restrict__ dst, int n) {
    int i = blockIdx.x*256 + threadIdx.x;
    if (i < n) dst[i] = __float2half_rn(src[i]);
}
__global__ __launch_bounds__(256) void k_cvt_str(const float* __restrict__ src,
                                                 __half* __restrict__ dst,
                                                 int rows, int rowLen, int srcStride) {
    int i = blockIdx.x*256 + threadIdx.x;
    if (i < rows*rowLen) {
        int r = i / rowLen, c = i - r*rowLen;
        dst[i] = __float2half_rn(src[(size_t)r*srcStride + c]);
    }
}

// ---------------------------------------------------------------------------
// Init: h0/h1 parity-0 row-major [64][512], cur(0) row [64][32]
__global__ __launch_bounds__(256) void k_init(const float* __restrict__ hidden,
                                              const float* __restrict__ inputs,
                                              float* __restrict__ h0r, float* __restrict__ h1r,
                                              float* __restrict__ curr) {
    int b = blockIdx.x, t = threadIdx.x;
    for (int k = t; k < NH; k += 256) {
        h0r[b*NH + k] = hidden[b*NH + k];
        h1r[b*NH + k] = hidden[NB*NH + b*NH + k];
    }
    if (t < NF) curr[b*NF + t] = inputs[b*NDEC*NF + t];
}

// ---------------------------------------------------------------------------
// enc_proj[be][g] = sum_h enc[be][h] * W_attn[g][512+h]; stored fp16
__global__ __launch_bounds__(256) void k_encproj(const float* __restrict__ enc,
                                                 const float* __restrict__ Wattn,
                                                 __half* __restrict__ encph) {
    __shared__ float As[64][17];
    __shared__ float Bs[64][17];
    int bx = blockIdx.x & 7;    // g tile
    int by = blockIdx.x >> 3;   // be tile
    int tid = threadIdx.x;
    int tx = tid & 15, ty = tid >> 4;
    int arow = tid >> 2;
    int akk  = (tid & 3) * 4;
    const float* Abase = enc   + (size_t)(by*64 + arow)*NH;
    const float* Bbase = Wattn + (size_t)(bx*64 + arow)*(2*NH) + NH;
    float acc[4][4] = {};
    for (int k0 = 0; k0 < NH; k0 += 16) {
        float4 av = *(const float4*)(Abase + k0 + akk);
        float4 bv = *(const float4*)(Bbase + k0 + akk);
        As[arow][akk+0] = av.x; As[arow][akk+1] = av.y;
        As[arow][akk+2] = av.z; As[arow][akk+3] = av.w;
        Bs[arow][akk+0] = bv.x; Bs[arow][akk+1] = bv.y;
        Bs[arow][akk+2] = bv.z; Bs[arow][akk+3] = bv.w;
        __syncthreads();
        #pragma unroll 4
        for (int k = 0; k < 16; ++k) {
            float a0 = As[ty*4+0][k], a1 = As[ty*4+1][k], a2 = As[ty*4+2][k], a3 = As[ty*4+3][k];
            float b0 = Bs[tx*4+0][k], b1 = Bs[tx*4+1][k], b2 = Bs[tx*4+2][k], b3 = Bs[tx*4+3][k];
            acc[0][0] += a0*b0; acc[0][1] += a0*b1; acc[0][2] += a0*b2; acc[0][3] += a0*b3;
            acc[1][0] += a1*b0; acc[1][1] += a1*b1; acc[1][2] += a1*b2; acc[1][3] += a1*b3;
            acc[2][0] += a2*b0; acc[2][1] += a2*b1; acc[2][2] += a2*b2; acc[2][3] += a2*b3;
            acc[3][0] += a3*b0; acc[3][1] += a3*b1; acc[3][2] += a3*b2; acc[3][3] += a3*b3;
        }
        __syncthreads();
    }
    #pragma unroll
    for (int i = 0; i < 4; ++i)
        #pragma unroll
        for (int j = 0; j < 4; ++j)
            encph[(size_t)(by*64 + ty*4 + i)*NH + bx*64 + tx*4 + j] = __float2half_rn(acc[i][j]);
}

// ---------------------------------------------------------------------------
// Fused per-step kernel: one block per batch element, 1024 threads.
// out-proj(s-1) + cur(s) + att GEMV (fp16 Wa_h) + scores (fp16 encp) + ws.
__global__ __launch_bounds__(1024) void k_step(
    const float* __restrict__ inputs, const int* __restrict__ tgt,
    const __half* __restrict__ Wah, const float* __restrict__ battn,
    const float* __restrict__ vattn,
    const __half* __restrict__ Wouth, const float* __restrict__ bout,
    const __half* __restrict__ encph, const float* __restrict__ enc,
    const float* __restrict__ h1row,   // [64][512] h1(s)
    float* __restrict__ wsr,           // [64][512]
    float* __restrict__ curr,          // [64][32]
    float* __restrict__ out,
    int s, int do_att)
{
    int b = blockIdx.x, t = threadIdx.x;
    int lane = t & 63, widx = t >> 6;
    __shared__ float h1s[NH], wsp[NH], vs[NH], atts[NH];
    __shared__ float pes[NE];
    __shared__ float combA[NH], combB[NH];
    __shared__ float outsh[NT];
    __shared__ float invD_sh;

    if (t < NH) { h1s[t] = h1row[b*NH + t]; vs[t] = vattn[t]; }
    else        { wsp[t - NH] = wsr[b*NH + (t - NH)]; }
    __syncthreads();

    if (s > 0) {
        if (widx < NT) {
            const __half* wr = Wouth + (size_t)widx*(2*NH + NF);
            float o = 0.f;
            for (int c = lane; c < 2*NH + NF; c += 64) {
                float x = (c < NH) ? h1s[c]
                        : (c < 2*NH ? wsp[c - NH] : curr[b*NF + (c - 2*NH)]);
                o += __half2float(wr[c]) * x;
            }
            #pragma unroll
            for (int off = 32; off; off >>= 1) o += __shfl_down(o, off);
            if (lane == 0) {
                o += bout[widx];
                outsh[widx] = o;
                out[b*(NDEC*NT) + (s-1)*NT + widx] = o;
            }
        }
        __syncthreads();
        if (do_att) {
            if (t < NF) curr[b*NF + t] = inputs[b*(NDEC*NF) + (s-1)*NF + t];
            __syncthreads();
            if (t < NT) curr[b*NF + tgt[t]] = outsh[t];
        }
    }
    if (!do_att) return;

    // att[g] = h1 . Wa_h[g] + battn[g]; thread = (g = t>>1, K-half = t&1)
    {
        int g = t >> 1, half = t & 1;
        const __half* wr = Wah + (size_t)g*NH + half*256;
        const float* hh = h1s + half*256;
        float acc = 0.f;
        #pragma unroll 8
        for (int i = 0; i < 256; i += 4) {
            float2 r = *(const float2*)(wr + i);
            __half2 h01 = *(__half2*)&r.x, h23 = *(__half2*)&r.y;
            float2 f01 = __half22float2(h01), f23 = __half22float2(h23);
            acc += f01.x*hh[i] + f01.y*hh[i+1] + f23.x*hh[i+2] + f23.y*hh[i+3];
        }
        acc += __shfl_xor(acc, 1);
        if (half == 0) atts[g] = acc + battn[g];
    }
    __syncthreads();

    // scores -> exp (no max-subtract: |score| small)
    {
        float ar[8], vr[8];
        #pragma unroll
        for (int i = 0; i < 8; ++i) { ar[i] = atts[lane*8 + i]; vr[i] = vs[lane*8 + i]; }
        for (int it = 0; it < 6; ++it) {
            int e = widx + it*16;
            const __half* ep = encph + ((size_t)(b*NE + e))*NH + lane*8;
            uint4 u = *(const uint4*)ep;
            __half2 p0 = *(__half2*)&u.x, p1 = *(__half2*)&u.y;
            __half2 p2 = *(__half2*)&u.z, p3 = *(__half2*)&u.w;
            float2 f0 = __half22float2(p0), f1 = __half22float2(p1);
            float2 f2 = __half22float2(p2), f3 = __half22float2(p3);
            float sacc;
            sacc  = fast_tanh(f0.x + ar[0]) * vr[0];
            sacc += fast_tanh(f0.y + ar[1]) * vr[1];
            sacc += fast_tanh(f1.x + ar[2]) * vr[2];
            sacc += fast_tanh(f1.y + ar[3]) * vr[3];
            sacc += fast_tanh(f2.x + ar[4]) * vr[4];
            sacc += fast_tanh(f2.y + ar[5]) * vr[5];
            sacc += fast_tanh(f3.x + ar[6]) * vr[6];
            sacc += fast_tanh(f3.y + ar[7]) * vr[7];
            #pragma unroll
            for (int off = 32; off; off >>= 1) sacc += __shfl_down(sacc, off);
            if (lane == 0) pes[e] = __expf(sacc);
        }
    }
    __syncthreads();

    if (t < 64) {
        float v = pes[t] + ((t < 32) ? pes[64 + t] : 0.f);
        #pragma unroll
        for (int off = 32; off; off >>= 1) v += __shfl_down(v, off);
        if (t == 0) invD_sh = 1.f / v;
    }
    __syncthreads();

    // ws[k] = sum_e p[e] * enc[b,e,k]
    {
        int k = t & 511, half = t >> 9;
        const float* eb = enc + ((size_t)b*NE + half*48)*NH + k;
        float acc = 0.f;
        #pragma unroll 4
        for (int e = 0; e < 48; ++e) acc += pes[half*48 + e] * eb[(size_t)e*NH];
        if (half == 0) combA[k] = acc; else combB[k] = acc;
    }
    __syncthreads();
    if (t < NH) wsr[b*NH + t] = (combA[t] + combB[t]) * invD_sh;
}

// ---------------------------------------------------------------------------
// fp16 weight 4-wide MAC helper
__device__ __forceinline__ void acc4h(const __half* wrow, int col, const float4& x4, float& acc) {
    float2 r = *(const float2*)(wrow + col);
    __half2 h01 = *(__half2*)&r.x, h23 = *(__half2*)&r.y;
    float2 f01 = __half22float2(h01), f23 = __half22float2(h23);
    acc += f01.x*x4.x + f01.y*x4.y + f23.x*x4.z + f23.y*x4.w;
}

// ---------------------------------------------------------------------------
// GRU: grid 256, block 512. Block = j pair {j0, j0+1}; thread = (b=t&63, kq=t>>6 of 8).
// Row-major fp32 state x[b][k]; fp16 weights. Virtual K = [xA(KA) | xB(KB) | hold(512)].
__global__ __launch_bounds__(512) void k_gru(
    const __half* __restrict__ Wi, const __half* __restrict__ Wh,
    const float* __restrict__ bi, const float* __restrict__ bh,
    const float* __restrict__ xA, int KA,     // [64][KA]
    const float* __restrict__ xB, int KB,     // [64][512] or null
    const float* __restrict__ hold,           // [64][512]
    float* __restrict__ hnew)                 // [64][512]
{
    int j0 = blockIdx.x * 2;
    int t = threadIdx.x, b = t & 63, kq = t >> 6;   // kq in 0..7
    int KIw = KA + KB;
    const __half* w0a = Wi + (size_t)j0*KIw;
    const __half* w1a = Wi + (size_t)(NH + j0)*KIw;
    const __half* w2a = Wi + (size_t)(2*NH + j0)*KIw;
    const __half* w0b = w0a + KIw; const __half* w1b = w1a + KIw; const __half* w2b = w2a + KIw;
    const __half* v0a = Wh + (size_t)j0*NH;
    const __half* v1a = Wh + (size_t)(NH + j0)*NH;
    const __half* v2a = Wh + (size_t)(2*NH + j0)*NH;
    const __half* v0b = v0a + NH; const __half* v1b = v1a + NH; const __half* v2b = v2a + NH;

    float A00 = 0.f, A01 = 0.f, A02 = 0.f, A03 = 0.f;   // j0: r, z, gi_n, gh_n
    float A10 = 0.f, A11 = 0.f, A12 = 0.f, A13 = 0.f;   // j0+1

    // segment 1: xA (Wi cols [0, KA))
    {
        int len = KA >> 3, k0 = kq*len, k1 = k0 + len;
        const float* xr = xA + b*KA;
        #pragma unroll 2
        for (int k = k0; k < k1; k += 4) {
            float4 x4 = *(const float4*)(xr + k);
            acc4h(w0a, k, x4, A00); acc4h(w1a, k, x4, A01); acc4h(w2a, k, x4, A02);
            acc4h(w0b, k, x4, A10); acc4h(w1b, k, x4, A11); acc4h(w2b, k, x4, A12);
        }
    }
    // segment 2: xB (Wi cols [KA, KA+KB))
    if (KB > 0) {
        int len = KB >> 3, k0 = kq*len, k1 = k0 + len;
        const float* xr = xB + b*NH;
        #pragma unroll 2
        for (int k = k0; k < k1; k += 4) {
            float4 x4 = *(const float4*)(xr + k);
            acc4h(w0a, KA + k, x4, A00); acc4h(w1a, KA + k, x4, A01); acc4h(w2a, KA + k, x4, A02);
            acc4h(w0b, KA + k, x4, A10); acc4h(w1b, KA + k, x4, A11); acc4h(w2b, KA + k, x4, A12);
        }
    }
    // segment 3: hold (Wh cols [0, 512))
    {
        int len = NH >> 3, k0 = kq*len, k1 = k0 + len;
        const float* xr = hold + b*NH;
        #pragma unroll 2
        for (int k = k0; k < k1; k += 4) {
            float4 x4 = *(const float4*)(xr + k);
            acc4h(v0a, k, x4, A00); acc4h(v1a, k, x4, A01); acc4h(v2a, k, x4, A03);
            acc4h(v0b, k, x4, A10); acc4h(v1b, k, x4, A11); acc4h(v2b, k, x4, A13);
        }
    }

    __shared__ float red[8][64][8];
    red[kq][b][0] = A00; red[kq][b][1] = A01; red[kq][b][2] = A02; red[kq][b][3] = A03;
    red[kq][b][4] = A10; red[kq][b][5] = A11; red[kq][b][6] = A12; red[kq][b][7] = A13;
    __syncthreads();
    if (t < 128) {
        int jl = t >> 6, bb = t & 63, j = j0 + jl, o = jl*4;
        float S0 = 0.f, S1 = 0.f, A2 = 0.f, G2 = 0.f;
        #pragma unroll
        for (int q = 0; q < 8; ++q) {
            S0 += red[q][bb][o+0]; S1 += red[q][bb][o+1];
            A2 += red[q][bb][o+2]; G2 += red[q][bb][o+3];
        }
        float r = fast_sig(S0 + bi[j] + bh[j]);
        float z = fast_sig(S1 + bi[NH + j] + bh[NH + j]);
        float n = fast_tanh(A2 + bi[2*NH + j] + r*(G2 + bh[2*NH + j]));
        float hp = hold[bb*NH + j];
        hnew[bb*NH + j] = (1.f - z)*n + z*hp;
    }
}

// ---------------------------------------------------------------------------
extern "C" void kernel_launch(void* const* d_in, const int* in_sizes, int n_in,
                              void* d_out, int out_size, void* d_ws, size_t ws_size,
                              hipStream_t stream) {
    const float* inputs = (const float*)d_in[0];
    const float* hidden = (const float*)d_in[1];
    const float* enc    = (const float*)d_in[2];
    const int*   tgt    = (const int*)d_in[3];
    const float* Wattn  = (const float*)d_in[4];
    const float* battn  = (const float*)d_in[5];
    const float* vattn  = (const float*)d_in[6];
    const float* Wi0    = (const float*)d_in[7];
    const float* Wh0    = (const float*)d_in[8];
    const float* bi0    = (const float*)d_in[9];
    const float* bh0    = (const float*)d_in[10];
    const float* Wi1    = (const float*)d_in[11];
    const float* Wh1    = (const float*)d_in[12];
    const float* bi1    = (const float*)d_in[13];
    const float* bh1    = (const float*)d_in[14];
    const float* Wout   = (const float*)d_in[15];
    const float* bout   = (const float*)d_in[16];
    float* out = (float*)d_out;

    // Workspace: fp32 state 663 KB + fp16 region 13.2 MB ≈ 13.9 MB
    float* h0r  = (float*)d_ws;               // 2 x [64][512]
    float* h1r  = h0r + 2*NB*NH;              // 2 x [64][512]
    float* wsr  = h1r + 2*NB*NH;              // [64][512]
    float* curr = wsr + NB*NH;                // [64][32]
    __half* Wi0h  = (__half*)(curr + NB*NF);  // 1536 x 544
    __half* Wh0h  = Wi0h + 1536*544;          // 1536 x 512
    __half* Wi1h  = Wh0h + 1536*512;
    __half* Wh1h  = Wi1h + 1536*512;
    __half* Wah   = Wh1h + 1536*512;          // 512 x 512 (W_attn[:, :512])
    __half* Wouth = Wah + 512*512;            // 4 x 1056
    __half* encph = Wouth + 4*1056;           // [6144][512]

    k_init<<<NB, 256, 0, stream>>>(hidden, inputs, h0r, h1r, curr);
    k_cvt<<<(1536*544 + 255)/256, 256, 0, stream>>>(Wi0, Wi0h, 1536*544);
    k_cvt<<<(1536*512 + 255)/256, 256, 0, stream>>>(Wh0, Wh0h, 1536*512);
    k_cvt<<<(1536*512 + 255)/256, 256, 0, stream>>>(Wi1, Wi1h, 1536*512);
    k_cvt<<<(1536*512 + 255)/256, 256, 0, stream>>>(Wh1, Wh1h, 1536*512);
    k_cvt<<<(4*1056 + 255)/256, 256, 0, stream>>>(Wout, Wouth, 4*1056);
    k_cvt_str<<<(512*512 + 255)/256, 256, 0, stream>>>(Wattn, Wah, 512, 512, 1024);
    k_encproj<<<768, 256, 0, stream>>>(enc, Wattn, encph);

    for (int s = 0; s < NDEC; ++s) {
        int par = s & 1;
        k_step<<<NB, 1024, 0, stream>>>(inputs, tgt, Wah, battn, vattn, Wouth, bout,
                                        encph, enc, h1r + par*NB*NH, wsr, curr, out, s, 1);
        k_gru<<<256, 512, 0, stream>>>(Wi0h, Wh0h, bi0, bh0,
                                       curr, NF, wsr, NH,
                                       h0r + par*NB*NH, h0r + (par^1)*NB*NH);
        k_gru<<<256, 512, 0, stream>>>(Wi1h, Wh1h, bi1, bh1,
                                       h0r + (par^1)*NB*NH, NH, nullptr, 0,
                                       h1r + par*NB*NH, h1r + (par^1)*NB*NH);
    }
    // Final out(11) projection only; h1(12) is in h1r parity 0
    k_step<<<NB, 1024, 0, stream>>>(inputs, tgt, Wah, battn, vattn, Wouth, bout,
                                    encph, enc, h1r, wsr, curr, out, NDEC, 0);
}

// Round 8
// 858.920 us; speedup vs baseline: 3.2821x; 1.2440x over previous
//
#include <hip/hip_runtime.h>
#include <hip/hip_fp16.h>

// Problem constants
#define NB   64     // batch
#define NDEC 12     // decoder steps
#define NF   32     // input features
#define NH   512    // hidden
#define NE   96     // encoder length
#define NT   4      // output dim

__device__ __forceinline__ float fast_tanh(float x) {
    x = fminf(fmaxf(x, -15.f), 15.f);
    float e = __expf(2.f * x);
    return (e - 1.f) / (e + 1.f);
}
__device__ __forceinline__ float fast_sig(float x) {
    return 1.f / (1.f + __expf(-x));
}

// ---------------------------------------------------------------------------
// One-time fused fp32 -> fp16 conversions (+ Wa_h transpose)
__global__ __launch_bounds__(256) void k_prep(
    const float* __restrict__ Wi0, const float* __restrict__ Wh0,
    const float* __restrict__ Wi1, const float* __restrict__ Wh1,
    const float* __restrict__ Wout, const float* __restrict__ Wattn,
    __half* __restrict__ Wi0h, __half* __restrict__ Wh0h,
    __half* __restrict__ Wi1h, __half* __restrict__ Wh1h,
    __half* __restrict__ Wouth, __half* __restrict__ WahT)
{
    int i = blockIdx.x*256 + threadIdx.x;
    const int n0 = 1536*544, n1 = 1536*512, n4 = 4*1056, n5 = 512*512;
    if (i < n0) { Wi0h[i] = __float2half_rn(Wi0[i]); return; }  i -= n0;
    if (i < n1) { Wh0h[i] = __float2half_rn(Wh0[i]); return; }  i -= n1;
    if (i < n1) { Wi1h[i] = __float2half_rn(Wi1[i]); return; }  i -= n1;
    if (i < n1) { Wh1h[i] = __float2half_rn(Wh1[i]); return; }  i -= n1;
    if (i < n4) { Wouth[i] = __float2half_rn(Wout[i]); return; } i -= n4;
    if (i < n5) {
        int k = i >> 9, g = i & 511;                 // WahT[k][g] = Wattn[g][k]
        WahT[i] = __float2half_rn(Wattn[(size_t)g*1024 + k]);
    }
}

// ---------------------------------------------------------------------------
// Init: h0/h1 col-major [512][64], h1 row copy [64][512], cur(0) col [32][64]
__global__ __launch_bounds__(256) void k_init(const float* __restrict__ hidden,
                                              const float* __restrict__ inputs,
                                              float* __restrict__ h0c, float* __restrict__ h1c,
                                              float* __restrict__ h1row,
                                              float* __restrict__ curc) {
    int b = blockIdx.x, t = threadIdx.x;
    for (int k = t; k < NH; k += 256) {
        float v0 = hidden[b*NH + k];
        float v1 = hidden[NB*NH + b*NH + k];
        h0c[k*NB + b] = v0;
        h1c[k*NB + b] = v1;
        h1row[b*NH + k] = v1;
    }
    if (t < NF) curc[t*NB + b] = inputs[b*NDEC*NF + t];
}

// ---------------------------------------------------------------------------
// enc_proj[be][g] = sum_h enc[be][h] * W_attn[g][512+h]; stored fp16
__global__ __launch_bounds__(256) void k_encproj(const float* __restrict__ enc,
                                                 const float* __restrict__ Wattn,
                                                 __half* __restrict__ encph) {
    __shared__ float As[64][17];
    __shared__ float Bs[64][17];
    int bx = blockIdx.x & 7;    // g tile
    int by = blockIdx.x >> 3;   // be tile
    int tid = threadIdx.x;
    int tx = tid & 15, ty = tid >> 4;
    int arow = tid >> 2;
    int akk  = (tid & 3) * 4;
    const float* Abase = enc   + (size_t)(by*64 + arow)*NH;
    const float* Bbase = Wattn + (size_t)(bx*64 + arow)*(2*NH) + NH;
    float acc[4][4] = {};
    for (int k0 = 0; k0 < NH; k0 += 16) {
        float4 av = *(const float4*)(Abase + k0 + akk);
        float4 bv = *(const float4*)(Bbase + k0 + akk);
        As[arow][akk+0] = av.x; As[arow][akk+1] = av.y;
        As[arow][akk+2] = av.z; As[arow][akk+3] = av.w;
        Bs[arow][akk+0] = bv.x; Bs[arow][akk+1] = bv.y;
        Bs[arow][akk+2] = bv.z; Bs[arow][akk+3] = bv.w;
        __syncthreads();
        #pragma unroll 4
        for (int k = 0; k < 16; ++k) {
            float a0 = As[ty*4+0][k], a1 = As[ty*4+1][k], a2 = As[ty*4+2][k], a3 = As[ty*4+3][k];
            float b0 = Bs[tx*4+0][k], b1 = Bs[tx*4+1][k], b2 = Bs[tx*4+2][k], b3 = Bs[tx*4+3][k];
            acc[0][0] += a0*b0; acc[0][1] += a0*b1; acc[0][2] += a0*b2; acc[0][3] += a0*b3;
            acc[1][0] += a1*b0; acc[1][1] += a1*b1; acc[1][2] += a1*b2; acc[1][3] += a1*b3;
            acc[2][0] += a2*b0; acc[2][1] += a2*b1; acc[2][2] += a2*b2; acc[2][3] += a2*b3;
            acc[3][0] += a3*b0; acc[3][1] += a3*b1; acc[3][2] += a3*b2; acc[3][3] += a3*b3;
        }
        __syncthreads();
    }
    #pragma unroll
    for (int i = 0; i < 4; ++i)
        #pragma unroll
        for (int j = 0; j < 4; ++j)
            encph[(size_t)(by*64 + ty*4 + i)*NH + bx*64 + tx*4 + j] = __float2half_rn(acc[i][j]);
}

// ---------------------------------------------------------------------------
// Fused per-step kernel: one block per batch element, 1024 threads.
// out-proj(s-1) + cur(s) + att GEMV (coalesced WahT) + scores + softmax + ws.
__global__ __launch_bounds__(1024) void k_step(
    const float* __restrict__ inputs, const int* __restrict__ tgt,
    const __half* __restrict__ WahT,   // [512 k][512 g]
    const float* __restrict__ battn, const float* __restrict__ vattn,
    const __half* __restrict__ Wouth, const float* __restrict__ bout,
    const __half* __restrict__ encph, const float* __restrict__ enc,
    const float* __restrict__ h1row,   // [64][512] h1(s)
    float* __restrict__ wsrow,         // [64][512]
    float* __restrict__ wscol,         // [512][64]
    float* __restrict__ curc,          // [32][64]
    float* __restrict__ out,
    int s, int do_att)
{
    int b = blockIdx.x, t = threadIdx.x;
    int lane = t & 63, widx = t >> 6;
    __shared__ float h1s[NH], wsp[NH], vs[NH], atts[NH];
    __shared__ float2 attp2[4][256];
    __shared__ float pes[NE], combA[NH], combB[NH], outsh[NT];
    __shared__ float invD_sh;

    if (t < NH) { h1s[t] = h1row[b*NH + t]; vs[t] = vattn[t]; }
    else        { wsp[t - NH] = wsrow[b*NH + (t - NH)]; }
    __syncthreads();

    if (s > 0) {
        if (widx < NT) {
            const __half* wr = Wouth + (size_t)widx*(2*NH + NF);
            float o = 0.f;
            for (int c = lane; c < 2*NH + NF; c += 64) {
                float x = (c < NH) ? h1s[c]
                        : (c < 2*NH ? wsp[c - NH] : curc[(c - 2*NH)*NB + b]);
                o += __half2float(wr[c]) * x;
            }
            #pragma unroll
            for (int off = 32; off; off >>= 1) o += __shfl_down(o, off);
            if (lane == 0) {
                o += bout[widx];
                outsh[widx] = o;
                out[b*(NDEC*NT) + (s-1)*NT + widx] = o;
            }
        }
        __syncthreads();
        if (do_att) {
            if (t < NF) curc[t*NB + b] = inputs[b*(NDEC*NF) + (s-1)*NF + t];
            __syncthreads();
            if (t < NT) curc[tgt[t]*NB + b] = outsh[t];
        }
    }
    if (!do_att) return;

    // att[g] = h1 . Wa_h[g] + battn[g]; coalesced: lane covers g-pairs
    {
        int g2 = t & 255, kq = t >> 8;   // 4 K-quarters of 128
        float a0 = 0.f, a1 = 0.f;
        #pragma unroll 4
        for (int k = kq*128; k < kq*128 + 128; ++k) {
            float2 f = __half22float2(*(const __half2*)(WahT + (size_t)k*NH + g2*2));
            float h = h1s[k];
            a0 += f.x*h; a1 += f.y*h;
        }
        attp2[kq][g2] = make_float2(a0, a1);
    }
    __syncthreads();
    if (t < NH) {
        int g = t;
        float2 p0 = attp2[0][g>>1], p1 = attp2[1][g>>1];
        float2 p2 = attp2[2][g>>1], p3 = attp2[3][g>>1];
        float v = (g & 1) ? (p0.y + p1.y + p2.y + p3.y)
                          : (p0.x + p1.x + p2.x + p3.x);
        atts[g] = v + battn[g];
    }
    __syncthreads();

    // scores -> exp (no max-subtract: |score| small)
    {
        float ar[8], vr[8];
        #pragma unroll
        for (int i = 0; i < 8; ++i) { ar[i] = atts[lane*8 + i]; vr[i] = vs[lane*8 + i]; }
        for (int it = 0; it < 6; ++it) {
            int e = widx + it*16;
            const __half* ep = encph + ((size_t)(b*NE + e))*NH + lane*8;
            uint4 u = *(const uint4*)ep;
            __half2 p0 = *(__half2*)&u.x, p1 = *(__half2*)&u.y;
            __half2 p2 = *(__half2*)&u.z, p3 = *(__half2*)&u.w;
            float2 f0 = __half22float2(p0), f1 = __half22float2(p1);
            float2 f2 = __half22float2(p2), f3 = __half22float2(p3);
            float sacc;
            sacc  = fast_tanh(f0.x + ar[0]) * vr[0];
            sacc += fast_tanh(f0.y + ar[1]) * vr[1];
            sacc += fast_tanh(f1.x + ar[2]) * vr[2];
            sacc += fast_tanh(f1.y + ar[3]) * vr[3];
            sacc += fast_tanh(f2.x + ar[4]) * vr[4];
            sacc += fast_tanh(f2.y + ar[5]) * vr[5];
            sacc += fast_tanh(f3.x + ar[6]) * vr[6];
            sacc += fast_tanh(f3.y + ar[7]) * vr[7];
            #pragma unroll
            for (int off = 32; off; off >>= 1) sacc += __shfl_down(sacc, off);
            if (lane == 0) pes[e] = __expf(sacc);
        }
    }
    __syncthreads();

    if (t < 64) {
        float v = pes[t] + ((t < 32) ? pes[64 + t] : 0.f);
        #pragma unroll
        for (int off = 32; off; off >>= 1) v += __shfl_down(v, off);
        if (t == 0) invD_sh = 1.f / v;
    }
    __syncthreads();

    // ws[k] = sum_e p[e] * enc[b,e,k]  (coalesced over k)
    {
        int k = t & 511, half = t >> 9;
        const float* eb = enc + ((size_t)b*NE + half*48)*NH + k;
        float acc = 0.f;
        #pragma unroll 4
        for (int e = 0; e < 48; ++e) acc += pes[half*48 + e] * eb[(size_t)e*NH];
        if (half == 0) combA[k] = acc; else combB[k] = acc;
    }
    __syncthreads();
    if (t < NH) {
        float v = (combA[t] + combB[t]) * invD_sh;
        wsrow[b*NH + t] = v;
        wscol[t*NB + b] = v;
    }
}

// ---------------------------------------------------------------------------
// GRU: grid 512 (block = one j), block 512 thr = (b = t&63, kq = t>>6 in [0,8)).
// Col-major fp32 state [k][64] (lane-coalesced); fp16 weights (wave-broadcast).
__global__ __launch_bounds__(512) void k_gru(
    const __half* __restrict__ Wi, const __half* __restrict__ Wh,
    const float* __restrict__ bi, const float* __restrict__ bh,
    const float* __restrict__ xA, int KA,     // [KA][64]
    const float* __restrict__ xB, int KB,     // [512][64] or null
    const float* __restrict__ holdc,          // [512][64]
    float* __restrict__ hnewc,                // [512][64]
    float* __restrict__ hnewrow)              // [64][512] or null
{
    int j = blockIdx.x;
    int t = threadIdx.x, b = t & 63, kq = t >> 6;
    int KIw = KA + KB;
    const __half* w0 = Wi + (size_t)j*KIw;
    const __half* w1 = Wi + (size_t)(NH + j)*KIw;
    const __half* w2 = Wi + (size_t)(2*NH + j)*KIw;
    const __half* v0 = Wh + (size_t)j*NH;
    const __half* v1 = Wh + (size_t)(NH + j)*NH;
    const __half* v2 = Wh + (size_t)(2*NH + j)*NH;
    float A0 = 0.f, A1 = 0.f, A2 = 0.f, A3 = 0.f;

    int lenA = KA >> 3;
    #pragma unroll 4
    for (int k = kq*lenA; k < kq*lenA + lenA; k += 2) {
        float x0 = xA[k*NB + b], x1 = xA[(k+1)*NB + b];
        float2 f0 = __half22float2(*(const __half2*)(w0 + k));
        float2 f1 = __half22float2(*(const __half2*)(w1 + k));
        float2 f2 = __half22float2(*(const __half2*)(w2 + k));
        A0 += f0.x*x0 + f0.y*x1;
        A1 += f1.x*x0 + f1.y*x1;
        A2 += f2.x*x0 + f2.y*x1;
    }
    if (KB > 0) {
        int lenB = KB >> 3;
        #pragma unroll 4
        for (int k = kq*lenB; k < kq*lenB + lenB; k += 2) {
            float x0 = xB[k*NB + b], x1 = xB[(k+1)*NB + b];
            int c = KA + k;
            float2 f0 = __half22float2(*(const __half2*)(w0 + c));
            float2 f1 = __half22float2(*(const __half2*)(w1 + c));
            float2 f2 = __half22float2(*(const __half2*)(w2 + c));
            A0 += f0.x*x0 + f0.y*x1;
            A1 += f1.x*x0 + f1.y*x1;
            A2 += f2.x*x0 + f2.y*x1;
        }
    }
    {
        int lenH = NH >> 3;   // 64
        #pragma unroll 4
        for (int k = kq*lenH; k < kq*lenH + lenH; k += 2) {
            float x0 = holdc[k*NB + b], x1 = holdc[(k+1)*NB + b];
            float2 f0 = __half22float2(*(const __half2*)(v0 + k));
            float2 f1 = __half22float2(*(const __half2*)(v1 + k));
            float2 f2 = __half22float2(*(const __half2*)(v2 + k));
            A0 += f0.x*x0 + f0.y*x1;
            A1 += f1.x*x0 + f1.y*x1;
            A3 += f2.x*x0 + f2.y*x1;
        }
    }

    __shared__ float red[8][64][4];
    red[kq][b][0] = A0; red[kq][b][1] = A1; red[kq][b][2] = A2; red[kq][b][3] = A3;
    __syncthreads();
    if (t < 64) {
        float S0 = 0.f, S1 = 0.f, S2 = 0.f, S3 = 0.f;
        #pragma unroll
        for (int q = 0; q < 8; ++q) {
            S0 += red[q][t][0]; S1 += red[q][t][1];
            S2 += red[q][t][2]; S3 += red[q][t][3];
        }
        float r = fast_sig(S0 + bi[j] + bh[j]);
        float z = fast_sig(S1 + bi[NH + j] + bh[NH + j]);
        float n = fast_tanh(S2 + bi[2*NH + j] + r*(S3 + bh[2*NH + j]));
        float hp = holdc[j*NB + t];
        float hv = (1.f - z)*n + z*hp;
        hnewc[j*NB + t] = hv;
        if (hnewrow) hnewrow[t*NH + j] = hv;
    }
}

// ---------------------------------------------------------------------------
extern "C" void kernel_launch(void* const* d_in, const int* in_sizes, int n_in,
                              void* d_out, int out_size, void* d_ws, size_t ws_size,
                              hipStream_t stream) {
    const float* inputs = (const float*)d_in[0];
    const float* hidden = (const float*)d_in[1];
    const float* enc    = (const float*)d_in[2];
    const int*   tgt    = (const int*)d_in[3];
    const float* Wattn  = (const float*)d_in[4];
    const float* battn  = (const float*)d_in[5];
    const float* vattn  = (const float*)d_in[6];
    const float* Wi0    = (const float*)d_in[7];
    const float* Wh0    = (const float*)d_in[8];
    const float* bi0    = (const float*)d_in[9];
    const float* bh0    = (const float*)d_in[10];
    const float* Wi1    = (const float*)d_in[11];
    const float* Wh1    = (const float*)d_in[12];
    const float* bi1    = (const float*)d_in[13];
    const float* bh1    = (const float*)d_in[14];
    const float* Wout   = (const float*)d_in[15];
    const float* bout   = (const float*)d_in[16];
    float* out = (float*)d_out;

    // Workspace: fp32 state ~0.93 MB + fp16 region ~13.2 MB ≈ 13.5 MiB
    float* h0c   = (float*)d_ws;              // 2 x [512][64]
    float* h1c   = h0c + 2*NH*NB;             // 2 x [512][64]
    float* h1row = h1c + 2*NH*NB;             // [64][512]
    float* wsrow = h1row + NB*NH;             // [64][512]
    float* wscol = wsrow + NB*NH;             // [512][64]
    float* curc  = wscol + NH*NB;             // [32][64]
    __half* Wi0h  = (__half*)(curc + NF*NB);  // 1536 x 544
    __half* Wh0h  = Wi0h + 1536*544;          // 1536 x 512
    __half* Wi1h  = Wh0h + 1536*512;          // 1536 x 512
    __half* Wh1h  = Wi1h + 1536*512;          // 1536 x 512
    __half* Wouth = Wh1h + 1536*512;          // 4 x 1056
    __half* WahT  = Wouth + 4*1056;           // [512 k][512 g]
    __half* encph = WahT + 512*512;           // [6144][512]

    k_init<<<NB, 256, 0, stream>>>(hidden, inputs, h0c, h1c, h1row, curc);
    k_prep<<<(1536*544 + 3*1536*512 + 4*1056 + 512*512 + 255)/256, 256, 0, stream>>>(
        Wi0, Wh0, Wi1, Wh1, Wout, Wattn, Wi0h, Wh0h, Wi1h, Wh1h, Wouth, WahT);
    k_encproj<<<768, 256, 0, stream>>>(enc, Wattn, encph);

    for (int s = 0; s < NDEC; ++s) {
        int par = s & 1;
        k_step<<<NB, 1024, 0, stream>>>(inputs, tgt, WahT, battn, vattn, Wouth, bout,
                                        encph, enc, h1row, wsrow, wscol, curc, out, s, 1);
        k_gru<<<NH, 512, 0, stream>>>(Wi0h, Wh0h, bi0, bh0,
                                      curc, NF, wscol, NH,
                                      h0c + par*NH*NB, h0c + (par^1)*NH*NB, nullptr);
        k_gru<<<NH, 512, 0, stream>>>(Wi1h, Wh1h, bi1, bh1,
                                      h0c + (par^1)*NH*NB, NH, nullptr, 0,
                                      h1c + par*NH*NB, h1c + (par^1)*NH*NB, h1row);
    }
    // Final out(11) projection only; h1row holds h1(12)
    k_step<<<NB, 1024, 0, stream>>>(inputs, tgt, WahT, battn, vattn, Wouth, bout,
                                    encph, enc, h1row, wsrow, wscol, curc, out, NDEC, 0);
}